// Round 5
// baseline (412.890 us; speedup 1.0000x reference)
//
#include <hip/hip_runtime.h>
#include <math.h>

#define N_TOK 2048
#define DIM   1024
#define BATCH 4

typedef float v4f  __attribute__((ext_vector_type(4)));
typedef __bf16 v8bf __attribute__((ext_vector_type(8)));
typedef unsigned short v8us __attribute__((ext_vector_type(8)));

static __device__ __forceinline__ unsigned short f2bf(float f) {
  unsigned int u = __float_as_uint(f);
  u += 0x7fffu + ((u >> 16) & 1u);          // round-to-nearest-even
  return (unsigned short)(u >> 16);
}
static __device__ __forceinline__ float bf2f(unsigned short h) {
  return __uint_as_float((unsigned int)h << 16);
}

// ------- fused: hs fp32->bf16 cast + qp projection + r_embed ---------------
__global__ __launch_bounds__(256) void castqp_kernel(
    const float* __restrict__ hs, const float* __restrict__ Wtq,
    const float* __restrict__ btq, unsigned short* __restrict__ hs_b,
    float2* __restrict__ qp, float2* __restrict__ remb) {
  int w = threadIdx.x >> 6, lane = threadIdx.x & 63;
  int row = blockIdx.x * 4 + w;
  const float* x = hs + (size_t)row * DIM;
  unsigned short* d = hs_b + (size_t)row * DIM;
  float a0 = 0.f, a1 = 0.f;
#pragma unroll
  for (int it = 0; it < 4; ++it) {
    int base = it * 256 + lane * 4;
    float4 v = *(const float4*)(x + base);
    float4 w0 = *(const float4*)(Wtq + base);
    float4 w1 = *(const float4*)(Wtq + DIM + base);
    ushort4 pk;
    pk.x = f2bf(v.x); pk.y = f2bf(v.y); pk.z = f2bf(v.z); pk.w = f2bf(v.w);
    *(ushort4*)(d + base) = pk;
    a0 += v.x * w0.x + v.y * w0.y + v.z * w0.z + v.w * w0.w;
    a1 += v.x * w1.x + v.y * w1.y + v.z * w1.z + v.w * w1.w;
  }
  for (int o = 32; o; o >>= 1) { a0 += __shfl_xor(a0, o); a1 += __shfl_xor(a1, o); }
  if (lane == 0) {
    a0 += btq[0]; a1 += btq[1];
    qp[row] = make_float2(a0, a1);
    float nrm = fmaxf(sqrtf(a0 * a0 + a1 * a1), 1e-12f);
    remb[row] = make_float2(a0 / nrm, a1 / nrm);
  }
}

// ---------------- 4 weight matrices in one launch (grid.y selects) --------
__global__ __launch_bounds__(256) void cast_w4_kernel(
    const float* __restrict__ W0, const float* __restrict__ W1,
    const float* __restrict__ W2, const float* __restrict__ W3,
    unsigned short* __restrict__ D0, unsigned short* __restrict__ D1,
    unsigned short* __restrict__ D2, unsigned short* __restrict__ D3) {
  const float* s;
  unsigned short* d;
  switch (blockIdx.y) {
    case 0: s = W0; d = D0; break;
    case 1: s = W1; d = D1; break;
    case 2: s = W2; d = D2; break;
    default: s = W3; d = D3; break;
  }
  int i = (blockIdx.x * 256 + threadIdx.x) * 4;
  float4 v = *(const float4*)(s + i);
  d[i + 0] = f2bf(v.x); d[i + 1] = f2bf(v.y);
  d[i + 2] = f2bf(v.z); d[i + 3] = f2bf(v.w);
}

// ---- pairwise dist_sq moments: two-stage, NO atomics ----------------------
__global__ __launch_bounds__(256) void moments_kernel(
    const float2* __restrict__ qp, double* __restrict__ part) {
  int b = blockIdx.y;
  int i0 = blockIdx.x * 32;
  const float2* qb = qp + ((size_t)b << 11);
  double s1 = 0.0, s2 = 0.0;
  for (int idx = threadIdx.x; idx < 32 * N_TOK; idx += 256) {
    int i = i0 + (idx >> 11), j = idx & (N_TOK - 1);
    float2 pi = qb[i], pj = qb[j];
    float dx = pi.x - pj.x, dy = pi.y - pj.y;
    float dd = __fadd_rn(__fmul_rn(dx, dx), __fmul_rn(dy, dy)); // match ref (no fma)
    s1 += (double)dd;
    s2 += (double)dd * (double)dd;
  }
  int lane = threadIdx.x & 63, w = threadIdx.x >> 6;
  for (int o = 32; o; o >>= 1) { s1 += __shfl_xor(s1, o); s2 += __shfl_xor(s2, o); }
  __shared__ double red[8];
  if (lane == 0) { red[w] = s1; red[4 + w] = s2; }
  __syncthreads();
  if (threadIdx.x == 0) {
    int slot = b * 64 + blockIdx.x;
    part[slot * 2 + 0] = red[0] + red[1] + red[2] + red[3];
    part[slot * 2 + 1] = red[4] + red[5] + red[6] + red[7];
  }
}

__global__ __launch_bounds__(256) void thr_kernel(
    const double* __restrict__ part, float* __restrict__ thr) {
  int b = threadIdx.x >> 6, lane = threadIdx.x & 63;
  double s1 = part[(b * 64 + lane) * 2 + 0];
  double s2 = part[(b * 64 + lane) * 2 + 1];
  for (int o = 32; o; o >>= 1) { s1 += __shfl_xor(s1, o); s2 += __shfl_xor(s2, o); }
  if (lane == 0) {
    double n2 = (double)N_TOK * (double)N_TOK;
    double mean = s1 / n2;
    double var = (s2 - n2 * mean * mean) / (n2 - 1.0); // ddof=1
    if (var < 0.0) var = 0.0;
    thr[b] = (float)(mean + 1.25 * sqrt(var));
  }
}

// ============ 128x128 tile K-loop (BK=64), m97-style =======================
__device__ __forceinline__ void gemm_ktile_loop(
    const unsigned short* __restrict__ Ag, const unsigned short* __restrict__ Bg,
    int ldA, int ldB, int kBeg, int kEnd,
    unsigned short* As, unsigned short* Bs, v4f acc[4][4]) {
  const int tid  = threadIdx.x;
  const int lane = tid & 63;
  const int wm   = ((tid >> 6) & 1) << 6, wn = (tid >> 7) << 6;
  const int quad = lane >> 4, l16 = lane & 15;
  const int srow = tid >> 3;
  const int scol = (tid & 7) * 8;
  for (int k0 = kBeg; k0 < kEnd; k0 += 64) {
    __syncthreads();
#pragma unroll
    for (int it = 0; it < 4; ++it) {
      int row = srow + it * 32;
      const unsigned short* ga = Ag + (size_t)row * ldA + k0 + scol;
      const unsigned short* gb = Bg + (size_t)row * ldB + k0 + scol;
      unsigned short* la = As + (size_t)(it * 256 + (tid & ~63)) * 8;
      unsigned short* lb = Bs + (size_t)(it * 256 + (tid & ~63)) * 8;
      __builtin_amdgcn_global_load_lds((const __attribute__((address_space(1))) void*)ga,
                                       (__attribute__((address_space(3))) void*)la, 16, 0, 0);
      __builtin_amdgcn_global_load_lds((const __attribute__((address_space(1))) void*)gb,
                                       (__attribute__((address_space(3))) void*)lb, 16, 0, 0);
    }
    asm volatile("s_waitcnt vmcnt(0)" ::: "memory");
    __syncthreads();
#pragma unroll
    for (int kk = 0; kk < 64; kk += 32) {
      v8bf af[4], bfv[4];
#pragma unroll
      for (int i = 0; i < 4; ++i)
        af[i] = *(const v8bf*)(As + (wm + i * 16 + l16) * 64 + kk + quad * 8);
#pragma unroll
      for (int i = 0; i < 4; ++i)
        bfv[i] = *(const v8bf*)(Bs + (wn + i * 16 + l16) * 64 + kk + quad * 8);
#pragma unroll
      for (int mi = 0; mi < 4; ++mi)
#pragma unroll
        for (int ni = 0; ni < 4; ++ni)
          acc[mi][ni] = __builtin_amdgcn_mfma_f32_16x16x32_bf16(af[mi], bfv[ni], acc[mi][ni], 0, 0, 0);
    }
  }
}

// ============ 64x128 tile K-loop (BK=64) ===================================
__device__ __forceinline__ void ktile64_loop(
    const unsigned short* __restrict__ Ag, const unsigned short* __restrict__ Bg,
    int ldA, int ldB, int kBeg, int kEnd,
    unsigned short* As, unsigned short* Bs, v4f acc[2][4]) {
  const int tid  = threadIdx.x;
  const int lane = tid & 63;
  const int wr   = ((tid >> 6) & 1) << 5, wc = (tid >> 7) << 6;
  const int quad = lane >> 4, l16 = lane & 15;
  const int srow = tid >> 3;
  const int scol = (tid & 7) * 8;
  for (int k0 = kBeg; k0 < kEnd; k0 += 64) {
    __syncthreads();
#pragma unroll
    for (int it = 0; it < 2; ++it) {
      const unsigned short* ga = Ag + (size_t)(srow + it * 32) * ldA + k0 + scol;
      unsigned short* la = As + (size_t)(it * 256 + (tid & ~63)) * 8;
      __builtin_amdgcn_global_load_lds((const __attribute__((address_space(1))) void*)ga,
                                       (__attribute__((address_space(3))) void*)la, 16, 0, 0);
    }
#pragma unroll
    for (int it = 0; it < 4; ++it) {
      const unsigned short* gb = Bg + (size_t)(srow + it * 32) * ldB + k0 + scol;
      unsigned short* lb = Bs + (size_t)(it * 256 + (tid & ~63)) * 8;
      __builtin_amdgcn_global_load_lds((const __attribute__((address_space(1))) void*)gb,
                                       (__attribute__((address_space(3))) void*)lb, 16, 0, 0);
    }
    asm volatile("s_waitcnt vmcnt(0)" ::: "memory");
    __syncthreads();
#pragma unroll
    for (int kk = 0; kk < 64; kk += 32) {
      v8bf af[2], bfv[4];
#pragma unroll
      for (int i = 0; i < 2; ++i)
        af[i] = *(const v8bf*)(As + (wr + i * 16 + l16) * 64 + kk + quad * 8);
#pragma unroll
      for (int i = 0; i < 4; ++i)
        bfv[i] = *(const v8bf*)(Bs + (wc + i * 16 + l16) * 64 + kk + quad * 8);
#pragma unroll
      for (int mi = 0; mi < 2; ++mi)
#pragma unroll
        for (int ni = 0; ni < 4; ++ni)
          acc[mi][ni] = __builtin_amdgcn_mfma_f32_16x16x32_bf16(af[mi], bfv[ni], acc[mi][ni], 0, 0, 0);
    }
  }
}

#define PROLOG128                                                     \
  __shared__ __attribute__((aligned(16))) unsigned short smem[2][128 * 64];\
  unsigned short* As = smem[0];                                       \
  unsigned short* Bs = smem[1];                                       \
  v4f acc[4][4];                                                      \
  _Pragma("unroll") for (int i_ = 0; i_ < 4; ++i_)                    \
  _Pragma("unroll") for (int j_ = 0; j_ < 4; ++j_)                    \
      acc[i_][j_] = v4f{0.f, 0.f, 0.f, 0.f};                          \
  const int lane = threadIdx.x & 63, w = threadIdx.x >> 6;            \
  const int wm = (w & 1) << 6, wn = (w >> 1) << 6;                    \
  const int quad = lane >> 4, l16 = lane & 15;

#define PROLOG64                                                      \
  __shared__ __attribute__((aligned(16))) unsigned short As[64 * 64]; \
  __shared__ __attribute__((aligned(16))) unsigned short Bs[128 * 64];\
  v4f acc[2][4];                                                      \
  _Pragma("unroll") for (int i_ = 0; i_ < 2; ++i_)                    \
  _Pragma("unroll") for (int j_ = 0; j_ < 4; ++j_)                    \
      acc[i_][j_] = v4f{0.f, 0.f, 0.f, 0.f};                          \
  const int lane = threadIdx.x & 63, w = threadIdx.x >> 6;            \
  const int wr = (w & 1) << 5, wc = (w >> 1) << 6;                    \
  const int quad = lane >> 4, l16 = lane & 15;

// ------- fused QKV: X[8192,1024] @ Wqkv[3072,1024]^T -----------------------
// XCD-slab swizzle: each XCD (id%8 round-robin heuristic) owns an 8-row X
// slab (2MB, fits 4MB L2) across all 24 W-columns -> X re-reads become L2
// hits (round-4 FETCH 77MB vs 23MB ideal = cross-XCD X re-fetch theory).
__global__ __launch_bounds__(256) void gemm_qkv_fused_kernel(
    const unsigned short* __restrict__ X, const unsigned short* __restrict__ Wqkv,
    const float* __restrict__ bq, const float* __restrict__ bk,
    const float* __restrict__ bv, unsigned short* __restrict__ q_b,
    unsigned short* __restrict__ k_b, unsigned short* __restrict__ v_t) {
  PROLOG128
  int lid = blockIdx.y * 24 + blockIdx.x;
  int xcd = lid & 7, slot = lid >> 3;
  int by = (xcd << 3) | (slot & 7);   // 0..63
  int bx = slot >> 3;                 // 0..23
  int m0 = by * 128, n0 = bx * 128;
  gemm_ktile_loop(X + (size_t)m0 * DIM, Wqkv + (size_t)n0 * DIM, DIM, DIM, 0, DIM, As, Bs, acc);
  int region = n0 >> 10;  // 0:q 1:k 2:v (block-uniform)
  const float* bias = region == 0 ? bq : region == 1 ? bk : bv;
  int cbase = n0 & 1023;
  if (region < 2) {
    unsigned short* dst = region == 0 ? q_b : k_b;
#pragma unroll
    for (int mi = 0; mi < 4; ++mi) {
      int row0 = m0 + wm + mi * 16 + quad * 4;
#pragma unroll
      for (int ni = 0; ni < 4; ++ni) {
        int col = cbase + wn + ni * 16 + l16;
        float bcol = bias[col];
#pragma unroll
        for (int r = 0; r < 4; ++r)
          dst[(size_t)(row0 + r) * DIM + col] = f2bf(acc[mi][ni][r] + bcol);
      }
    }
  } else {
    // transpose tile through LDS, then coalesced 256B feature-row stores
    unsigned short* T = &smem[0][0];
    __syncthreads();
#pragma unroll
    for (int mi = 0; mi < 4; ++mi) {
      int trow = wm + mi * 16 + quad * 4;
#pragma unroll
      for (int ni = 0; ni < 4; ++ni) {
        int fcol = wn + ni * 16 + l16;
        float bcol = bias[cbase + fcol];
        ushort4 pk;
        pk.x = f2bf(acc[mi][ni][0] + bcol);
        pk.y = f2bf(acc[mi][ni][1] + bcol);
        pk.z = f2bf(acc[mi][ni][2] + bcol);
        pk.w = f2bf(acc[mi][ni][3] + bcol);
        *(ushort4*)(T + fcol * 128 + trow) = pk;
      }
    }
    __syncthreads();
    int bb = m0 >> 11, tok0 = m0 & (N_TOK - 1);
    unsigned short* dstb = v_t + ((size_t)(bb << 10) + cbase) * N_TOK + tok0;
#pragma unroll
    for (int kk2 = 0; kk2 < 8; ++kk2) {
      int c = kk2 * 256 + threadIdx.x;
      int f = c >> 4, e0 = (c & 15) * 8;
      v8us v = *(const v8us*)(T + f * 128 + e0);
      *(v8us*)(dstb + (size_t)f * N_TOK + e0) = v;
    }
  }
}

// ------- scores: 64x128 tiles, triangular; S stored bf16 -------------------
static __device__ __forceinline__ int tri_cum(int T) {
  int m = T >> 1;
  return (T & 1) ? (m + 1) * (m + 1) : m * (m + 1);
}
__global__ __launch_bounds__(256) void gemm_scores_kernel(
    const unsigned short* __restrict__ q, const unsigned short* __restrict__ k,
    const float2* __restrict__ qp, const float* __restrict__ thr,
    unsigned short* __restrict__ S) {
  PROLOG64
  int b = blockIdx.y;
  int t = blockIdx.x;
  int ti = 2 * (int)sqrtf((float)t);
  if (ti > 31) ti = 31;
  while (ti < 31 && tri_cum(ti + 1) <= t) ++ti;
  while (tri_cum(ti) > t) --ti;
  int tj = t - tri_cum(ti);
  int i0 = ti * 64, j0 = tj * 128;
  const unsigned short* qb = q + (size_t)b * N_TOK * DIM;
  const unsigned short* kb = k + (size_t)b * N_TOK * DIM;
  ktile64_loop(qb + (size_t)i0 * DIM, kb + (size_t)j0 * DIM, DIM, DIM, 0, DIM, As, Bs, acc);
  float th = thr[b];
  const float2* qpb = qp + ((size_t)b << 11);
  unsigned short* Sb = S + (size_t)b * N_TOK * N_TOK;
  float2 pjv[4];
#pragma unroll
  for (int ni = 0; ni < 4; ++ni) pjv[ni] = qpb[j0 + wc + ni * 16 + l16];
#pragma unroll
  for (int mi = 0; mi < 2; ++mi) {
#pragma unroll
    for (int r = 0; r < 4; ++r) {
      int i = i0 + wr + mi * 16 + quad * 4 + r;
      float2 pi2 = qpb[i];
#pragma unroll
      for (int ni = 0; ni < 4; ++ni) {
        int j = j0 + wc + ni * 16 + l16;
        if (j <= i) {
          float dx = pi2.x - pjv[ni].x, dy = pi2.y - pjv[ni].y;
          float dd = __fadd_rn(__fmul_rn(dx, dx), __fmul_rn(dy, dy));
          bool ok = (dd <= th);
          // forward_bias==0 only when cos(atan2) rounds to -1 (dx<0, |dy| tiny)
          if (ok && dx < 0.f && fabsf(dy) <= 3e-4f * (-dx)) {
            float fb = 0.5f * (1.f + cosf(atan2f(dy, dx)));
            if (fb == 0.f) ok = false;
          }
          Sb[(size_t)i * N_TOK + j] = ok ? f2bf(acc[mi][ni][r] * 0.03125f) : 0xFF80; // -inf bf16
        }
      }
    }
  }
}

// ------- per-row softmax stats: (max, 1/sum) from S, one wave per row ------
__global__ __launch_bounds__(256) void stats_kernel(
    const unsigned short* __restrict__ S, float2* __restrict__ stats) {
  int w = threadIdx.x >> 6, lane = threadIdx.x & 63;
  int row = blockIdx.x * 4 + w;
  int b = row >> 11, i = row & (N_TOK - 1);
  const unsigned short* s = S + ((size_t)b * N_TOK + i) * N_TOK;
  int lim = i + 1;
  float mx = -__builtin_inff();
  for (int j = lane * 8; j < lim; j += 512) {
    if (j + 8 <= lim) {
      v8us v = *(const v8us*)(s + j);
#pragma unroll
      for (int e = 0; e < 8; ++e) mx = fmaxf(mx, bf2f(v[e]));
    } else {
      for (int e = 0; e < lim - j; ++e) mx = fmaxf(mx, bf2f(s[j + e]));
    }
  }
  for (int o = 32; o; o >>= 1) mx = fmaxf(mx, __shfl_xor(mx, o));
  float sum = 0.f;
  for (int j = lane * 8; j < lim; j += 512) {
    if (j + 8 <= lim) {
      v8us v = *(const v8us*)(s + j);
#pragma unroll
      for (int e = 0; e < 8; ++e) sum += __expf(bf2f(v[e]) - mx);
    } else {
      for (int e = 0; e < lim - j; ++e) sum += __expf(bf2f(s[j + e]) - mx);
    }
  }
  for (int o = 32; o; o >>= 1) sum += __shfl_xor(sum, o);
  if (lane == 0) stats[row] = make_float2(mx, 1.f / sum);
}

// ------- context = softmax(S) @ v, fused exp in A-staging ------------------
// A-operand: load S bf16, apply exp(s-m)*inv in-register (identical numerics
// to the old materialized P = f2bf(exp*inv)), ds_write_b128 to LDS. B (v_t)
// stays global_load_lds. Eliminates the 33.6MB P buffer + softmax pass.
__global__ __launch_bounds__(256) void gemm_pv_kernel(
    const unsigned short* __restrict__ S, const float2* __restrict__ stats,
    const unsigned short* __restrict__ vt, unsigned short* __restrict__ ctx) {
  __shared__ __attribute__((aligned(16))) unsigned short As[64 * 64];
  __shared__ __attribute__((aligned(16))) unsigned short Bs[128 * 64];
  v4f acc[2][4];
#pragma unroll
  for (int i_ = 0; i_ < 2; ++i_)
#pragma unroll
    for (int j_ = 0; j_ < 4; ++j_) acc[i_][j_] = v4f{0.f, 0.f, 0.f, 0.f};
  const int tid = threadIdx.x, lane = tid & 63, w = tid >> 6;
  const int wr = (w & 1) << 5, wc = (w >> 1) << 6;
  const int quad = lane >> 4, l16 = lane & 15;
  const int srow = tid >> 3, scol = (tid & 7) * 8;
  int b = blockIdx.z, ti = blockIdx.y, d0 = blockIdx.x * 128, i0 = ti * 64;
  const unsigned short* Sb = S + (size_t)b * N_TOK * N_TOK;
  const unsigned short* Vb = vt + ((size_t)b * DIM + d0) * N_TOK;
  const float2* stb = stats + ((size_t)b << 11);
  float2 st[2] = {stb[i0 + srow], stb[i0 + srow + 32]};
  int kEnd = ((ti + 2) >> 1) * 128;  // covers j <= i0+63
  for (int k0 = 0; k0 < kEnd; k0 += 64) {
    __syncthreads();
#pragma unroll
    for (int it = 0; it < 2; ++it) {
      int r = srow + it * 32, gi = i0 + r, gj = k0 + scol;
      v8us sv = *(const v8us*)(Sb + (size_t)gi * N_TOK + gj);
      v8us pk8;
#pragma unroll
      for (int e = 0; e < 8; ++e)
        pk8[e] = (gj + e <= gi)
                     ? f2bf(__expf(bf2f(sv[e]) - st[it].x) * st[it].y)
                     : (unsigned short)0;
      *(v8us*)(As + r * 64 + scol) = pk8;
    }
#pragma unroll
    for (int it = 0; it < 4; ++it) {
      const unsigned short* gb = Vb + (size_t)(srow + it * 32) * N_TOK + k0 + scol;
      unsigned short* lb = Bs + (size_t)(it * 256 + (tid & ~63)) * 8;
      __builtin_amdgcn_global_load_lds((const __attribute__((address_space(1))) void*)gb,
                                       (__attribute__((address_space(3))) void*)lb, 16, 0, 0);
    }
    asm volatile("s_waitcnt vmcnt(0)" ::: "memory");
    __syncthreads();
#pragma unroll
    for (int kk = 0; kk < 64; kk += 32) {
      v8bf af[2], bfv[4];
#pragma unroll
      for (int i = 0; i < 2; ++i)
        af[i] = *(const v8bf*)(As + (wr + i * 16 + l16) * 64 + kk + quad * 8);
#pragma unroll
      for (int i = 0; i < 4; ++i)
        bfv[i] = *(const v8bf*)(Bs + (wc + i * 16 + l16) * 64 + kk + quad * 8);
#pragma unroll
      for (int mi = 0; mi < 2; ++mi)
#pragma unroll
        for (int ni = 0; ni < 4; ++ni)
          acc[mi][ni] = __builtin_amdgcn_mfma_f32_16x16x32_bf16(af[mi], bfv[ni], acc[mi][ni], 0, 0, 0);
    }
  }
#pragma unroll
  for (int mi = 0; mi < 2; ++mi) {
    int row0 = i0 + wr + mi * 16 + quad * 4;
#pragma unroll
    for (int ni = 0; ni < 4; ++ni) {
      int d = d0 + wc + ni * 16 + l16;
#pragma unroll
      for (int r = 0; r < 4; ++r)
        ctx[((size_t)b * N_TOK + row0 + r) * DIM + d] = f2bf(acc[mi][ni][r]);
    }
  }
}

// ------- out = hs + ctx@Wo^T + bo + 0.1*(r_embed@Wfq^T + bfq), 64x128 -----
__global__ __launch_bounds__(256) void gemm_out_kernel(
    const unsigned short* __restrict__ ctx, const unsigned short* __restrict__ Wob,
    const float* __restrict__ bo, const float* __restrict__ hs,
    const float2* __restrict__ remb, const float* __restrict__ Wfq,
    const float* __restrict__ bfq, float* __restrict__ out) {
  PROLOG64
  int lid = blockIdx.y * 8 + blockIdx.x;
  int xcd = lid & 7, slot = lid >> 3;
  int by = (xcd << 4) | (slot & 15);  // 0..127 (16-row slab per XCD)
  int bx = slot >> 4;                 // 0..7
  int m0 = by * 64, n0 = bx * 128;
  ktile64_loop(ctx + (size_t)m0 * DIM, Wob + (size_t)n0 * DIM, DIM, DIM, 0, DIM, As, Bs, acc);
#pragma unroll
  for (int mi = 0; mi < 2; ++mi) {
    int row0 = m0 + wr + mi * 16 + quad * 4;
#pragma unroll
    for (int ni = 0; ni < 4; ++ni) {
      int col = n0 + wc + ni * 16 + l16;
      float bias2 = bo[col] + 0.1f * bfq[col];
      float wf0 = 0.1f * Wfq[col * 2 + 0], wf1 = 0.1f * Wfq[col * 2 + 1];
#pragma unroll
      for (int r = 0; r < 4; ++r) {
        int row = row0 + r;
        float2 re = remb[row];
        out[(size_t)row * DIM + col] =
            acc[mi][ni][r] + bias2 + hs[(size_t)row * DIM + col] + re.x * wf0 + re.y * wf1;
      }
    }
  }
}

extern "C" void kernel_launch(void* const* d_in, const int* in_sizes, int n_in,
                              void* d_out, int out_size, void* d_ws, size_t ws_size,
                              hipStream_t stream) {
  const float* hs  = (const float*)d_in[0];
  const float* Wq  = (const float*)d_in[1];
  const float* bq  = (const float*)d_in[2];
  const float* Wk  = (const float*)d_in[3];
  const float* bk  = (const float*)d_in[4];
  const float* Wv  = (const float*)d_in[5];
  const float* bv  = (const float*)d_in[6];
  const float* Wo  = (const float*)d_in[7];
  const float* bo  = (const float*)d_in[8];
  const float* Wtq = (const float*)d_in[9];
  const float* btq = (const float*)d_in[10];
  const float* Wfq = (const float*)d_in[11];
  const float* bfq = (const float*)d_in[12];
  float* out = (float*)d_out;

  char* ws = (char*)d_ws;
  size_t off = 0;
  auto alloc = [&](size_t bytes) {
    char* p = ws + off;
    off += (bytes + 255) & ~(size_t)255;
    return p;
  };
  unsigned short* hs_b = (unsigned short*)alloc((size_t)8192 * 1024 * 2);  // 16.8MB
  unsigned short* q_b  = (unsigned short*)alloc((size_t)8192 * 1024 * 2);
  unsigned short* k_b  = (unsigned short*)alloc((size_t)8192 * 1024 * 2);
  unsigned short* v_t  = (unsigned short*)alloc((size_t)8192 * 1024 * 2);
  // Wq_b/Wk_b/Wv_b MUST stay contiguous: fused QKV uses them as one [3072,1024].
  unsigned short* Wq_b = (unsigned short*)alloc((size_t)1024 * 1024 * 2);
  unsigned short* Wk_b = (unsigned short*)alloc((size_t)1024 * 1024 * 2);
  unsigned short* Wv_b = (unsigned short*)alloc((size_t)1024 * 1024 * 2);
  unsigned short* Wo_b = (unsigned short*)alloc((size_t)1024 * 1024 * 2);
  float2* qp    = (float2*)alloc((size_t)8192 * 8);
  float2* remb  = (float2*)alloc((size_t)8192 * 8);
  float2* stats = (float2*)alloc((size_t)8192 * 8);
  double* part  = (double*)alloc((size_t)BATCH * 64 * 2 * 8);
  float*  thr   = (float*)alloc(64);
  unsigned short* S = (unsigned short*)alloc((size_t)BATCH * N_TOK * N_TOK * 2);  // 33.6MB bf16
  // Alias (lifetimes disjoint): ctx over hs_b (hs_b last read by QKV GEMM).
  unsigned short* ctx = hs_b;

  castqp_kernel<<<2048, 256, 0, stream>>>(hs, Wtq, btq, hs_b, qp, remb);
  cast_w4_kernel<<<dim3(1024, 4), 256, 0, stream>>>(Wq, Wk, Wv, Wo, Wq_b, Wk_b, Wv_b, Wo_b);
  moments_kernel<<<dim3(64, BATCH), 256, 0, stream>>>((const float2*)qp, part);
  thr_kernel<<<1, 256, 0, stream>>>(part, thr);

  gemm_qkv_fused_kernel<<<dim3(24, 64), 256, 0, stream>>>(
      hs_b, Wq_b, bq, bk, bv, q_b, k_b, v_t);

  gemm_scores_kernel<<<dim3(272, 4), 256, 0, stream>>>(
      q_b, k_b, (const float2*)qp, thr, S);

  stats_kernel<<<2048, 256, 0, stream>>>(S, stats);

  gemm_pv_kernel<<<dim3(8, 32, 4), 256, 0, stream>>>(S, (const float2*)stats, v_t, ctx);

  gemm_out_kernel<<<dim3(8, 128), 256, 0, stream>>>(ctx, Wo_b, bo, hs, remb, Wfq, bfq, out);
}

// Round 6
// 378.545 us; speedup vs baseline: 1.0907x; 1.0907x over previous
//
#include <hip/hip_runtime.h>
#include <math.h>

#define N_TOK 2048
#define DIM   1024
#define BATCH 4

typedef float v4f  __attribute__((ext_vector_type(4)));
typedef __bf16 v8bf __attribute__((ext_vector_type(8)));
typedef unsigned short v8us __attribute__((ext_vector_type(8)));

static __device__ __forceinline__ unsigned short f2bf(float f) {
  unsigned int u = __float_as_uint(f);
  u += 0x7fffu + ((u >> 16) & 1u);          // round-to-nearest-even
  return (unsigned short)(u >> 16);
}
static __device__ __forceinline__ float bf2f(unsigned short h) {
  return __uint_as_float((unsigned int)h << 16);
}

// ------- fused: hs fp32->bf16 cast + qp projection + r_embed ---------------
__global__ __launch_bounds__(256) void castqp_kernel(
    const float* __restrict__ hs, const float* __restrict__ Wtq,
    const float* __restrict__ btq, unsigned short* __restrict__ hs_b,
    float2* __restrict__ qp, float2* __restrict__ remb) {
  int w = threadIdx.x >> 6, lane = threadIdx.x & 63;
  int row = blockIdx.x * 4 + w;
  const float* x = hs + (size_t)row * DIM;
  unsigned short* d = hs_b + (size_t)row * DIM;
  float a0 = 0.f, a1 = 0.f;
#pragma unroll
  for (int it = 0; it < 4; ++it) {
    int base = it * 256 + lane * 4;
    float4 v = *(const float4*)(x + base);
    float4 w0 = *(const float4*)(Wtq + base);
    float4 w1 = *(const float4*)(Wtq + DIM + base);
    ushort4 pk;
    pk.x = f2bf(v.x); pk.y = f2bf(v.y); pk.z = f2bf(v.z); pk.w = f2bf(v.w);
    *(ushort4*)(d + base) = pk;
    a0 += v.x * w0.x + v.y * w0.y + v.z * w0.z + v.w * w0.w;
    a1 += v.x * w1.x + v.y * w1.y + v.z * w1.z + v.w * w1.w;
  }
  for (int o = 32; o; o >>= 1) { a0 += __shfl_xor(a0, o); a1 += __shfl_xor(a1, o); }
  if (lane == 0) {
    a0 += btq[0]; a1 += btq[1];
    qp[row] = make_float2(a0, a1);
    float nrm = fmaxf(sqrtf(a0 * a0 + a1 * a1), 1e-12f);
    remb[row] = make_float2(a0 / nrm, a1 / nrm);
  }
}

// ---------------- 4 weight matrices in one launch (grid.y selects) --------
__global__ __launch_bounds__(256) void cast_w4_kernel(
    const float* __restrict__ W0, const float* __restrict__ W1,
    const float* __restrict__ W2, const float* __restrict__ W3,
    unsigned short* __restrict__ D0, unsigned short* __restrict__ D1,
    unsigned short* __restrict__ D2, unsigned short* __restrict__ D3) {
  const float* s;
  unsigned short* d;
  switch (blockIdx.y) {
    case 0: s = W0; d = D0; break;
    case 1: s = W1; d = D1; break;
    case 2: s = W2; d = D2; break;
    default: s = W3; d = D3; break;
  }
  int i = (blockIdx.x * 256 + threadIdx.x) * 4;
  float4 v = *(const float4*)(s + i);
  d[i + 0] = f2bf(v.x); d[i + 1] = f2bf(v.y);
  d[i + 2] = f2bf(v.z); d[i + 3] = f2bf(v.w);
}

// ---- pairwise dist_sq moments: two-stage, NO atomics ----------------------
__global__ __launch_bounds__(256) void moments_kernel(
    const float2* __restrict__ qp, double* __restrict__ part) {
  int b = blockIdx.y;
  int i0 = blockIdx.x * 32;
  const float2* qb = qp + ((size_t)b << 11);
  double s1 = 0.0, s2 = 0.0;
  for (int idx = threadIdx.x; idx < 32 * N_TOK; idx += 256) {
    int i = i0 + (idx >> 11), j = idx & (N_TOK - 1);
    float2 pi = qb[i], pj = qb[j];
    float dx = pi.x - pj.x, dy = pi.y - pj.y;
    float dd = __fadd_rn(__fmul_rn(dx, dx), __fmul_rn(dy, dy)); // match ref (no fma)
    s1 += (double)dd;
    s2 += (double)dd * (double)dd;
  }
  int lane = threadIdx.x & 63, w = threadIdx.x >> 6;
  for (int o = 32; o; o >>= 1) { s1 += __shfl_xor(s1, o); s2 += __shfl_xor(s2, o); }
  __shared__ double red[8];
  if (lane == 0) { red[w] = s1; red[4 + w] = s2; }
  __syncthreads();
  if (threadIdx.x == 0) {
    int slot = b * 64 + blockIdx.x;
    part[slot * 2 + 0] = red[0] + red[1] + red[2] + red[3];
    part[slot * 2 + 1] = red[4] + red[5] + red[6] + red[7];
  }
}

__global__ __launch_bounds__(256) void thr_kernel(
    const double* __restrict__ part, float* __restrict__ thr) {
  int b = threadIdx.x >> 6, lane = threadIdx.x & 63;
  double s1 = part[(b * 64 + lane) * 2 + 0];
  double s2 = part[(b * 64 + lane) * 2 + 1];
  for (int o = 32; o; o >>= 1) { s1 += __shfl_xor(s1, o); s2 += __shfl_xor(s2, o); }
  if (lane == 0) {
    double n2 = (double)N_TOK * (double)N_TOK;
    double mean = s1 / n2;
    double var = (s2 - n2 * mean * mean) / (n2 - 1.0); // ddof=1
    if (var < 0.0) var = 0.0;
    thr[b] = (float)(mean + 1.25 * sqrt(var));
  }
}

// ============ 128x128 tile K-loop (BK=64), m97-style =======================
__device__ __forceinline__ void gemm_ktile_loop(
    const unsigned short* __restrict__ Ag, const unsigned short* __restrict__ Bg,
    int ldA, int ldB, int kBeg, int kEnd,
    unsigned short* As, unsigned short* Bs, v4f acc[4][4]) {
  const int tid  = threadIdx.x;
  const int lane = tid & 63;
  const int wm   = ((tid >> 6) & 1) << 6, wn = (tid >> 7) << 6;
  const int quad = lane >> 4, l16 = lane & 15;
  const int srow = tid >> 3;
  const int scol = (tid & 7) * 8;
  for (int k0 = kBeg; k0 < kEnd; k0 += 64) {
    __syncthreads();
#pragma unroll
    for (int it = 0; it < 4; ++it) {
      int row = srow + it * 32;
      const unsigned short* ga = Ag + (size_t)row * ldA + k0 + scol;
      const unsigned short* gb = Bg + (size_t)row * ldB + k0 + scol;
      unsigned short* la = As + (size_t)(it * 256 + (tid & ~63)) * 8;
      unsigned short* lb = Bs + (size_t)(it * 256 + (tid & ~63)) * 8;
      __builtin_amdgcn_global_load_lds((const __attribute__((address_space(1))) void*)ga,
                                       (__attribute__((address_space(3))) void*)la, 16, 0, 0);
      __builtin_amdgcn_global_load_lds((const __attribute__((address_space(1))) void*)gb,
                                       (__attribute__((address_space(3))) void*)lb, 16, 0, 0);
    }
    asm volatile("s_waitcnt vmcnt(0)" ::: "memory");
    __syncthreads();
#pragma unroll
    for (int kk = 0; kk < 64; kk += 32) {
      v8bf af[4], bfv[4];
#pragma unroll
      for (int i = 0; i < 4; ++i)
        af[i] = *(const v8bf*)(As + (wm + i * 16 + l16) * 64 + kk + quad * 8);
#pragma unroll
      for (int i = 0; i < 4; ++i)
        bfv[i] = *(const v8bf*)(Bs + (wn + i * 16 + l16) * 64 + kk + quad * 8);
#pragma unroll
      for (int mi = 0; mi < 4; ++mi)
#pragma unroll
        for (int ni = 0; ni < 4; ++ni)
          acc[mi][ni] = __builtin_amdgcn_mfma_f32_16x16x32_bf16(af[mi], bfv[ni], acc[mi][ni], 0, 0, 0);
    }
  }
}

// ============ 64x64 tile K-loop (BK=64) — max block count ==================
// 4 waves 2x2: wr in {0,32}, wc in {0,32}; acc[2][2]. LDS 8KB A + 8KB B.
__device__ __forceinline__ void ktile6464_loop(
    const unsigned short* __restrict__ Ag, const unsigned short* __restrict__ Bg,
    int ldA, int ldB, int kEnd,
    unsigned short* As, unsigned short* Bs, v4f acc[2][2]) {
  const int tid  = threadIdx.x;
  const int lane = tid & 63;
  const int wr   = ((tid >> 6) & 1) << 5, wc = (tid >> 7) << 5;
  const int quad = lane >> 4, l16 = lane & 15;
  const int srow = tid >> 3;
  const int scol = (tid & 7) * 8;
  for (int k0 = 0; k0 < kEnd; k0 += 64) {
    __syncthreads();
#pragma unroll
    for (int it = 0; it < 2; ++it) {
      const unsigned short* ga = Ag + (size_t)(srow + it * 32) * ldA + k0 + scol;
      unsigned short* la = As + (size_t)(it * 256 + (tid & ~63)) * 8;
      __builtin_amdgcn_global_load_lds((const __attribute__((address_space(1))) void*)ga,
                                       (__attribute__((address_space(3))) void*)la, 16, 0, 0);
    }
#pragma unroll
    for (int it = 0; it < 2; ++it) {
      const unsigned short* gb = Bg + (size_t)(srow + it * 32) * ldB + k0 + scol;
      unsigned short* lb = Bs + (size_t)(it * 256 + (tid & ~63)) * 8;
      __builtin_amdgcn_global_load_lds((const __attribute__((address_space(1))) void*)gb,
                                       (__attribute__((address_space(3))) void*)lb, 16, 0, 0);
    }
    asm volatile("s_waitcnt vmcnt(0)" ::: "memory");
    __syncthreads();
#pragma unroll
    for (int kk = 0; kk < 64; kk += 32) {
      v8bf af[2], bfv[2];
#pragma unroll
      for (int i = 0; i < 2; ++i)
        af[i] = *(const v8bf*)(As + (wr + i * 16 + l16) * 64 + kk + quad * 8);
#pragma unroll
      for (int i = 0; i < 2; ++i)
        bfv[i] = *(const v8bf*)(Bs + (wc + i * 16 + l16) * 64 + kk + quad * 8);
#pragma unroll
      for (int mi = 0; mi < 2; ++mi)
#pragma unroll
        for (int ni = 0; ni < 2; ++ni)
          acc[mi][ni] = __builtin_amdgcn_mfma_f32_16x16x32_bf16(af[mi], bfv[ni], acc[mi][ni], 0, 0, 0);
    }
  }
}

#define PROLOG128                                                     \
  __shared__ __attribute__((aligned(16))) unsigned short smem[2][128 * 64];\
  unsigned short* As = smem[0];                                       \
  unsigned short* Bs = smem[1];                                       \
  v4f acc[4][4];                                                      \
  _Pragma("unroll") for (int i_ = 0; i_ < 4; ++i_)                    \
  _Pragma("unroll") for (int j_ = 0; j_ < 4; ++j_)                    \
      acc[i_][j_] = v4f{0.f, 0.f, 0.f, 0.f};                          \
  const int lane = threadIdx.x & 63, w = threadIdx.x >> 6;            \
  const int wm = (w & 1) << 6, wn = (w >> 1) << 6;                    \
  const int quad = lane >> 4, l16 = lane & 15;

#define PROLOG6464                                                    \
  __shared__ __attribute__((aligned(16))) unsigned short As[64 * 64]; \
  __shared__ __attribute__((aligned(16))) unsigned short Bs[64 * 64]; \
  v4f acc[2][2];                                                      \
  _Pragma("unroll") for (int i_ = 0; i_ < 2; ++i_)                    \
  _Pragma("unroll") for (int j_ = 0; j_ < 2; ++j_)                    \
      acc[i_][j_] = v4f{0.f, 0.f, 0.f, 0.f};                          \
  const int lane = threadIdx.x & 63, w = threadIdx.x >> 6;            \
  const int wr = (w & 1) << 5, wc = (w >> 1) << 5;                    \
  const int quad = lane >> 4, l16 = lane & 15;

// ------- fused QKV: X[8192,1024] @ Wqkv[3072,1024]^T -----------------------
// XCD-slab swizzle (VERIFIED round 5: FETCH 77->49MB): each XCD owns an
// 8-row X slab (2MB, fits 4MB L2) across all 24 W-columns.
__global__ __launch_bounds__(256) void gemm_qkv_fused_kernel(
    const unsigned short* __restrict__ X, const unsigned short* __restrict__ Wqkv,
    const float* __restrict__ bq, const float* __restrict__ bk,
    const float* __restrict__ bv, unsigned short* __restrict__ q_b,
    unsigned short* __restrict__ k_b, unsigned short* __restrict__ v_t) {
  PROLOG128
  int lid = blockIdx.y * 24 + blockIdx.x;
  int xcd = lid & 7, slot = lid >> 3;
  int by = (xcd << 3) | (slot & 7);   // 0..63
  int bx = slot >> 3;                 // 0..23
  int m0 = by * 128, n0 = bx * 128;
  gemm_ktile_loop(X + (size_t)m0 * DIM, Wqkv + (size_t)n0 * DIM, DIM, DIM, 0, DIM, As, Bs, acc);
  int region = n0 >> 10;  // 0:q 1:k 2:v (block-uniform)
  const float* bias = region == 0 ? bq : region == 1 ? bk : bv;
  int cbase = n0 & 1023;
  if (region < 2) {
    unsigned short* dst = region == 0 ? q_b : k_b;
#pragma unroll
    for (int mi = 0; mi < 4; ++mi) {
      int row0 = m0 + wm + mi * 16 + quad * 4;
#pragma unroll
      for (int ni = 0; ni < 4; ++ni) {
        int col = cbase + wn + ni * 16 + l16;
        float bcol = bias[col];
#pragma unroll
        for (int r = 0; r < 4; ++r)
          dst[(size_t)(row0 + r) * DIM + col] = f2bf(acc[mi][ni][r] + bcol);
      }
    }
  } else {
    // transpose tile through LDS, then coalesced 256B feature-row stores
    unsigned short* T = &smem[0][0];
    __syncthreads();
#pragma unroll
    for (int mi = 0; mi < 4; ++mi) {
      int trow = wm + mi * 16 + quad * 4;
#pragma unroll
      for (int ni = 0; ni < 4; ++ni) {
        int fcol = wn + ni * 16 + l16;
        float bcol = bias[cbase + fcol];
        ushort4 pk;
        pk.x = f2bf(acc[mi][ni][0] + bcol);
        pk.y = f2bf(acc[mi][ni][1] + bcol);
        pk.z = f2bf(acc[mi][ni][2] + bcol);
        pk.w = f2bf(acc[mi][ni][3] + bcol);
        *(ushort4*)(T + fcol * 128 + trow) = pk;
      }
    }
    __syncthreads();
    int bb = m0 >> 11, tok0 = m0 & (N_TOK - 1);
    unsigned short* dstb = v_t + ((size_t)(bb << 10) + cbase) * N_TOK + tok0;
#pragma unroll
    for (int kk2 = 0; kk2 < 8; ++kk2) {
      int c = kk2 * 256 + threadIdx.x;
      int f = c >> 4, e0 = (c & 15) * 8;
      v8us v = *(const v8us*)(T + f * 128 + e0);
      *(v8us*)(dstb + (size_t)f * N_TOK + e0) = v;
    }
  }
}

// ------- scores: 64x64 tiles, triangular (528/batch, 2112 blocks) ----------
// XCD swizzle: contiguous 66-tile triangular chunk per XCD -> q-panel L2 reuse.
__global__ __launch_bounds__(256) void gemm_scores_kernel(
    const unsigned short* __restrict__ q, const unsigned short* __restrict__ k,
    const float2* __restrict__ qp, const float* __restrict__ thr,
    unsigned short* __restrict__ S) {
  PROLOG6464
  int b = blockIdx.y;
  int bx = blockIdx.x;
  int t = (bx & 7) * 66 + (bx >> 3);  // 528 = 8 XCDs x 66 contiguous tiles
  int ti = (int)((sqrtf(8.f * (float)t + 1.f) - 1.f) * 0.5f);
  while ((ti + 1) * (ti + 2) / 2 <= t) ++ti;
  while (ti * (ti + 1) / 2 > t) --ti;
  int tj = t - ti * (ti + 1) / 2;
  int i0 = ti * 64, j0 = tj * 64;
  const unsigned short* qb = q + (size_t)b * N_TOK * DIM;
  const unsigned short* kb = k + (size_t)b * N_TOK * DIM;
  ktile6464_loop(qb + (size_t)i0 * DIM, kb + (size_t)j0 * DIM, DIM, DIM, DIM, As, Bs, acc);
  float th = thr[b];
  const float2* qpb = qp + ((size_t)b << 11);
  unsigned short* Sb = S + (size_t)b * N_TOK * N_TOK;
  float2 pjv[2];
#pragma unroll
  for (int ni = 0; ni < 2; ++ni) pjv[ni] = qpb[j0 + wc + ni * 16 + l16];
#pragma unroll
  for (int mi = 0; mi < 2; ++mi) {
#pragma unroll
    for (int r = 0; r < 4; ++r) {
      int i = i0 + wr + mi * 16 + quad * 4 + r;
      float2 pi2 = qpb[i];
#pragma unroll
      for (int ni = 0; ni < 2; ++ni) {
        int j = j0 + wc + ni * 16 + l16;
        if (j <= i) {
          float dx = pi2.x - pjv[ni].x, dy = pi2.y - pjv[ni].y;
          float dd = __fadd_rn(__fmul_rn(dx, dx), __fmul_rn(dy, dy));
          bool ok = (dd <= th);
          // forward_bias==0 only when cos(atan2) rounds to -1 (dx<0, |dy| tiny)
          if (ok && dx < 0.f && fabsf(dy) <= 3e-4f * (-dx)) {
            float fb = 0.5f * (1.f + cosf(atan2f(dy, dx)));
            if (fb == 0.f) ok = false;
          }
          Sb[(size_t)i * N_TOK + j] = ok ? f2bf(acc[mi][ni][r] * 0.03125f) : 0xFF80; // -inf bf16
        }
      }
    }
  }
}

// ------- row softmax: S bf16 (j<=i) -> P bf16 (full row), vectorized -------
__global__ __launch_bounds__(256) void softmax_kernel(
    const unsigned short* __restrict__ S, unsigned short* __restrict__ P) {
  int row = blockIdx.x;
  int b = row >> 11, i = row & (N_TOK - 1);
  const unsigned short* s = S + ((size_t)b * N_TOK + i) * N_TOK;
  unsigned short* p = P + ((size_t)b * N_TOK + i) * N_TOK;
  int tid = threadIdx.x, lane = tid & 63, w = tid >> 6;
  int lim = i + 1;
  int tail0 = lim & ~7, ntail = lim - tail0;
  __shared__ float redmax[4], redsum[4];
  float mx = -__builtin_inff();
  for (int j = tid * 8; j + 8 <= lim; j += 2048) {
    v8us v = *(const v8us*)(s + j);
#pragma unroll
    for (int e = 0; e < 8; ++e) mx = fmaxf(mx, bf2f(v[e]));
  }
  if (tid < ntail) mx = fmaxf(mx, bf2f(s[tail0 + tid]));
  for (int o = 32; o; o >>= 1) mx = fmaxf(mx, __shfl_xor(mx, o));
  if (lane == 0) redmax[w] = mx;
  __syncthreads();
  mx = fmaxf(fmaxf(redmax[0], redmax[1]), fmaxf(redmax[2], redmax[3]));
  float sum = 0.f;
  for (int j = tid * 8; j + 8 <= lim; j += 2048) {
    v8us v = *(const v8us*)(s + j);
#pragma unroll
    for (int e = 0; e < 8; ++e) sum += __expf(bf2f(v[e]) - mx);
  }
  if (tid < ntail) sum += __expf(bf2f(s[tail0 + tid]) - mx);
  for (int o = 32; o; o >>= 1) sum += __shfl_xor(sum, o);
  if (lane == 0) redsum[w] = sum;
  __syncthreads();
  sum = redsum[0] + redsum[1] + redsum[2] + redsum[3];
  float inv = 1.f / sum;
  for (int j = tid * 8; j + 8 <= lim; j += 2048) {
    v8us v = *(const v8us*)(s + j);
    v8us o;
#pragma unroll
    for (int e = 0; e < 8; ++e) o[e] = f2bf(__expf(bf2f(v[e]) - mx) * inv);
    *(v8us*)(p + j) = o;
  }
  if (tid < ntail) p[tail0 + tid] = f2bf(__expf(bf2f(s[tail0 + tid]) - mx) * inv);
  int zs = (lim + 7) & ~7;
  if (tid < zs - lim) p[lim + tid] = 0;
  v8us zv;
#pragma unroll
  for (int e = 0; e < 8; ++e) zv[e] = 0;
  for (int j = zs + tid * 8; j < N_TOK; j += 2048) *(v8us*)(p + j) = zv;
}

// ------- context = P @ v (v transposed), 64x64 tiles, triangular K --------
// Natural x&7 XCD mapping: each XCD owns 2 v feature-slabs (L2 reuse).
__global__ __launch_bounds__(256) void gemm_pv_kernel(
    const unsigned short* __restrict__ P, const unsigned short* __restrict__ vt,
    unsigned short* __restrict__ ctx) {
  PROLOG6464
  int b = blockIdx.z;
  int ti = blockIdx.y, d0 = blockIdx.x * 64;
  int i0 = ti * 64;
  const unsigned short* Pb = P + (size_t)b * N_TOK * N_TOK;
  const unsigned short* Vb = vt + ((size_t)b * DIM + d0) * N_TOK;
  int kEnd = (ti + 1) * 64;  // P[i][j]==0 for j>i
  ktile6464_loop(Pb + (size_t)i0 * N_TOK, Vb, N_TOK, N_TOK, kEnd, As, Bs, acc);
#pragma unroll
  for (int mi = 0; mi < 2; ++mi) {
    int row0 = i0 + wr + mi * 16 + quad * 4;
#pragma unroll
    for (int ni = 0; ni < 2; ++ni) {
      int d = d0 + wc + ni * 16 + l16;
#pragma unroll
      for (int r = 0; r < 4; ++r)
        ctx[((size_t)b * N_TOK + row0 + r) * DIM + d] = f2bf(acc[mi][ni][r]);
    }
  }
}

// ------- out = hs + ctx@Wo^T + bo + 0.1*(r_embed@Wfq^T + bfq), 64x64 ------
// XCD ctx-row-slab swizzle (Wo_b is 2MB -> L2-resident on every XCD anyway).
__global__ __launch_bounds__(256) void gemm_out_kernel(
    const unsigned short* __restrict__ ctx, const unsigned short* __restrict__ Wob,
    const float* __restrict__ bo, const float* __restrict__ hs,
    const float2* __restrict__ remb, const float* __restrict__ Wfq,
    const float* __restrict__ bfq, float* __restrict__ out) {
  PROLOG6464
  int lid = blockIdx.y * 16 + blockIdx.x;
  int xcd = lid & 7, slot = lid >> 3;
  int by = (xcd << 4) | (slot & 15);  // 0..127 (16-row slab per XCD)
  int bx = slot >> 4;                 // 0..15
  int m0 = by * 64, n0 = bx * 64;
  ktile6464_loop(ctx + (size_t)m0 * DIM, Wob + (size_t)n0 * DIM, DIM, DIM, DIM, As, Bs, acc);
#pragma unroll
  for (int mi = 0; mi < 2; ++mi) {
    int row0 = m0 + wr + mi * 16 + quad * 4;
#pragma unroll
    for (int ni = 0; ni < 2; ++ni) {
      int col = n0 + wc + ni * 16 + l16;
      float bias2 = bo[col] + 0.1f * bfq[col];
      float wf0 = 0.1f * Wfq[col * 2 + 0], wf1 = 0.1f * Wfq[col * 2 + 1];
#pragma unroll
      for (int r = 0; r < 4; ++r) {
        int row = row0 + r;
        float2 re = remb[row];
        out[(size_t)row * DIM + col] =
            acc[mi][ni][r] + bias2 + hs[(size_t)row * DIM + col] + re.x * wf0 + re.y * wf1;
      }
    }
  }
}

extern "C" void kernel_launch(void* const* d_in, const int* in_sizes, int n_in,
                              void* d_out, int out_size, void* d_ws, size_t ws_size,
                              hipStream_t stream) {
  const float* hs  = (const float*)d_in[0];
  const float* Wq  = (const float*)d_in[1];
  const float* bq  = (const float*)d_in[2];
  const float* Wk  = (const float*)d_in[3];
  const float* bk  = (const float*)d_in[4];
  const float* Wv  = (const float*)d_in[5];
  const float* bv  = (const float*)d_in[6];
  const float* Wo  = (const float*)d_in[7];
  const float* bo  = (const float*)d_in[8];
  const float* Wtq = (const float*)d_in[9];
  const float* btq = (const float*)d_in[10];
  const float* Wfq = (const float*)d_in[11];
  const float* bfq = (const float*)d_in[12];
  float* out = (float*)d_out;

  char* ws = (char*)d_ws;
  size_t off = 0;
  auto alloc = [&](size_t bytes) {
    char* p = ws + off;
    off += (bytes + 255) & ~(size_t)255;
    return p;
  };
  unsigned short* hs_b = (unsigned short*)alloc((size_t)8192 * 1024 * 2);  // 16.8MB
  unsigned short* q_b  = (unsigned short*)alloc((size_t)8192 * 1024 * 2);
  unsigned short* k_b  = (unsigned short*)alloc((size_t)8192 * 1024 * 2);  // contiguous after q_b (P alias)
  unsigned short* v_t  = (unsigned short*)alloc((size_t)8192 * 1024 * 2);
  // Wq_b/Wk_b/Wv_b MUST stay contiguous: fused QKV uses them as one [3072,1024].
  unsigned short* Wq_b = (unsigned short*)alloc((size_t)1024 * 1024 * 2);
  unsigned short* Wk_b = (unsigned short*)alloc((size_t)1024 * 1024 * 2);
  unsigned short* Wv_b = (unsigned short*)alloc((size_t)1024 * 1024 * 2);
  unsigned short* Wo_b = (unsigned short*)alloc((size_t)1024 * 1024 * 2);
  float2* qp   = (float2*)alloc((size_t)8192 * 8);
  float2* remb = (float2*)alloc((size_t)8192 * 8);
  double* part = (double*)alloc((size_t)BATCH * 64 * 2 * 8);
  float*  thr  = (float*)alloc(64);
  unsigned short* S = (unsigned short*)alloc((size_t)BATCH * N_TOK * N_TOK * 2);  // 33.6MB bf16
  // Aliases (lifetimes disjoint): P over q_b+k_b (33.6MB, both dead after
  // scores), ctx over hs_b (dead after QKV).
  unsigned short* P   = q_b;
  unsigned short* ctx = hs_b;

  castqp_kernel<<<2048, 256, 0, stream>>>(hs, Wtq, btq, hs_b, qp, remb);
  cast_w4_kernel<<<dim3(1024, 4), 256, 0, stream>>>(Wq, Wk, Wv, Wo, Wq_b, Wk_b, Wv_b, Wo_b);
  moments_kernel<<<dim3(64, BATCH), 256, 0, stream>>>((const float2*)qp, part);
  thr_kernel<<<1, 256, 0, stream>>>(part, thr);

  gemm_qkv_fused_kernel<<<dim3(24, 64), 256, 0, stream>>>(
      hs_b, Wq_b, bq, bk, bv, q_b, k_b, v_t);

  gemm_scores_kernel<<<dim3(528, 4), 256, 0, stream>>>(
      q_b, k_b, (const float2*)qp, thr, S);

  softmax_kernel<<<8192, 256, 0, stream>>>(S, P);

  gemm_pv_kernel<<<dim3(16, 32, 4), 256, 0, stream>>>(P, v_t, ctx);

  gemm_out_kernel<<<dim3(16, 128), 256, 0, stream>>>(ctx, Wo_b, bo, hs, remb, Wfq, bfq, out);
}

// Round 7
// 335.645 us; speedup vs baseline: 1.2301x; 1.1278x over previous
//
#include <hip/hip_runtime.h>
#include <math.h>

#define N_TOK 2048
#define DIM   1024
#define BATCH 4

typedef float v4f  __attribute__((ext_vector_type(4)));
typedef __bf16 v8bf __attribute__((ext_vector_type(8)));
typedef unsigned short v8us __attribute__((ext_vector_type(8)));

static __device__ __forceinline__ unsigned short f2bf(float f) {
  unsigned int u = __float_as_uint(f);
  u += 0x7fffu + ((u >> 16) & 1u);          // round-to-nearest-even
  return (unsigned short)(u >> 16);
}
static __device__ __forceinline__ float bf2f(unsigned short h) {
  return __uint_as_float((unsigned int)h << 16);
}

// ------- fused: hs fp32->bf16 cast + qp projection + r_embed ---------------
__global__ __launch_bounds__(256) void castqp_kernel(
    const float* __restrict__ hs, const float* __restrict__ Wtq,
    const float* __restrict__ btq, unsigned short* __restrict__ hs_b,
    float2* __restrict__ qp, float2* __restrict__ remb) {
  int w = threadIdx.x >> 6, lane = threadIdx.x & 63;
  int row = blockIdx.x * 4 + w;
  const float* x = hs + (size_t)row * DIM;
  unsigned short* d = hs_b + (size_t)row * DIM;
  float a0 = 0.f, a1 = 0.f;
#pragma unroll
  for (int it = 0; it < 4; ++it) {
    int base = it * 256 + lane * 4;
    float4 v = *(const float4*)(x + base);
    float4 w0 = *(const float4*)(Wtq + base);
    float4 w1 = *(const float4*)(Wtq + DIM + base);
    ushort4 pk;
    pk.x = f2bf(v.x); pk.y = f2bf(v.y); pk.z = f2bf(v.z); pk.w = f2bf(v.w);
    *(ushort4*)(d + base) = pk;
    a0 += v.x * w0.x + v.y * w0.y + v.z * w0.z + v.w * w0.w;
    a1 += v.x * w1.x + v.y * w1.y + v.z * w1.z + v.w * w1.w;
  }
  for (int o = 32; o; o >>= 1) { a0 += __shfl_xor(a0, o); a1 += __shfl_xor(a1, o); }
  if (lane == 0) {
    a0 += btq[0]; a1 += btq[1];
    qp[row] = make_float2(a0, a1);
    float nrm = fmaxf(sqrtf(a0 * a0 + a1 * a1), 1e-12f);
    remb[row] = make_float2(a0 / nrm, a1 / nrm);
  }
}

// ---------------- 4 weight matrices in one launch (grid.y selects) --------
__global__ __launch_bounds__(256) void cast_w4_kernel(
    const float* __restrict__ W0, const float* __restrict__ W1,
    const float* __restrict__ W2, const float* __restrict__ W3,
    unsigned short* __restrict__ D0, unsigned short* __restrict__ D1,
    unsigned short* __restrict__ D2, unsigned short* __restrict__ D3) {
  const float* s;
  unsigned short* d;
  switch (blockIdx.y) {
    case 0: s = W0; d = D0; break;
    case 1: s = W1; d = D1; break;
    case 2: s = W2; d = D2; break;
    default: s = W3; d = D3; break;
  }
  int i = (blockIdx.x * 256 + threadIdx.x) * 4;
  float4 v = *(const float4*)(s + i);
  d[i + 0] = f2bf(v.x); d[i + 1] = f2bf(v.y);
  d[i + 2] = f2bf(v.z); d[i + 3] = f2bf(v.w);
}

// ---- pairwise dist_sq moments: two-stage, NO atomics ----------------------
__global__ __launch_bounds__(256) void moments_kernel(
    const float2* __restrict__ qp, double* __restrict__ part) {
  int b = blockIdx.y;
  int i0 = blockIdx.x * 32;
  const float2* qb = qp + ((size_t)b << 11);
  double s1 = 0.0, s2 = 0.0;
  for (int idx = threadIdx.x; idx < 32 * N_TOK; idx += 256) {
    int i = i0 + (idx >> 11), j = idx & (N_TOK - 1);
    float2 pi = qb[i], pj = qb[j];
    float dx = pi.x - pj.x, dy = pi.y - pj.y;
    float dd = __fadd_rn(__fmul_rn(dx, dx), __fmul_rn(dy, dy)); // match ref (no fma)
    s1 += (double)dd;
    s2 += (double)dd * (double)dd;
  }
  int lane = threadIdx.x & 63, w = threadIdx.x >> 6;
  for (int o = 32; o; o >>= 1) { s1 += __shfl_xor(s1, o); s2 += __shfl_xor(s2, o); }
  __shared__ double red[8];
  if (lane == 0) { red[w] = s1; red[4 + w] = s2; }
  __syncthreads();
  if (threadIdx.x == 0) {
    int slot = b * 64 + blockIdx.x;
    part[slot * 2 + 0] = red[0] + red[1] + red[2] + red[3];
    part[slot * 2 + 1] = red[4] + red[5] + red[6] + red[7];
  }
}

__global__ __launch_bounds__(256) void thr_kernel(
    const double* __restrict__ part, float* __restrict__ thr) {
  int b = threadIdx.x >> 6, lane = threadIdx.x & 63;
  double s1 = part[(b * 64 + lane) * 2 + 0];
  double s2 = part[(b * 64 + lane) * 2 + 1];
  for (int o = 32; o; o >>= 1) { s1 += __shfl_xor(s1, o); s2 += __shfl_xor(s2, o); }
  if (lane == 0) {
    double n2 = (double)N_TOK * (double)N_TOK;
    double mean = s1 / n2;
    double var = (s2 - n2 * mean * mean) / (n2 - 1.0); // ddof=1
    if (var < 0.0) var = 0.0;
    thr[b] = (float)(mean + 1.25 * sqrt(var));
  }
}

// ============ 128x128 tile K-loop (BK=64), XOR-swizzled LDS ================
// LDS rows are 128B -> naive ds_read_b128 puts all 16 lanes of a quarter on
// one bank group (round-6: SQ_LDS_BANK_CONFLICT 2.08e7/dispatch ~35% of
// cycles). Staging lane fetches global granule (tid&7)^(srow&7); reader uses
// physical granule g^(row&7). row&7==l16&7 for all fragment rows, so the
// swizzle is one XOR per fragment batch. Bit-identical data.
__device__ __forceinline__ void gemm_ktile_loop(
    const unsigned short* __restrict__ Ag, const unsigned short* __restrict__ Bg,
    int ldA, int ldB, int kBeg, int kEnd,
    unsigned short* As, unsigned short* Bs, v4f acc[4][4]) {
  const int tid  = threadIdx.x;
  const int lane = tid & 63;
  const int wm   = ((tid >> 6) & 1) << 6, wn = (tid >> 7) << 6;
  const int quad = lane >> 4, l16 = lane & 15;
  const int srow = tid >> 3;
  const int scol = ((tid ^ srow) & 7) * 8;   // XOR-swizzled global granule
  for (int k0 = kBeg; k0 < kEnd; k0 += 64) {
    __syncthreads();
#pragma unroll
    for (int it = 0; it < 4; ++it) {
      int row = srow + it * 32;
      const unsigned short* ga = Ag + (size_t)row * ldA + k0 + scol;
      const unsigned short* gb = Bg + (size_t)row * ldB + k0 + scol;
      unsigned short* la = As + (size_t)(it * 256 + (tid & ~63)) * 8;
      unsigned short* lb = Bs + (size_t)(it * 256 + (tid & ~63)) * 8;
      __builtin_amdgcn_global_load_lds((const __attribute__((address_space(1))) void*)ga,
                                       (__attribute__((address_space(3))) void*)la, 16, 0, 0);
      __builtin_amdgcn_global_load_lds((const __attribute__((address_space(1))) void*)gb,
                                       (__attribute__((address_space(3))) void*)lb, 16, 0, 0);
    }
    asm volatile("s_waitcnt vmcnt(0)" ::: "memory");
    __syncthreads();
#pragma unroll
    for (int kk = 0; kk < 64; kk += 32) {
      const int co = ((((kk >> 3) + quad) ^ (l16 & 7)) << 3);
      v8bf af[4], bfv[4];
#pragma unroll
      for (int i = 0; i < 4; ++i)
        af[i] = *(const v8bf*)(As + (wm + i * 16 + l16) * 64 + co);
#pragma unroll
      for (int i = 0; i < 4; ++i)
        bfv[i] = *(const v8bf*)(Bs + (wn + i * 16 + l16) * 64 + co);
#pragma unroll
      for (int mi = 0; mi < 4; ++mi)
#pragma unroll
        for (int ni = 0; ni < 4; ++ni)
          acc[mi][ni] = __builtin_amdgcn_mfma_f32_16x16x32_bf16(af[mi], bfv[ni], acc[mi][ni], 0, 0, 0);
    }
  }
}

// ============ 64x64 tile K-loop (BK=64), XOR-swizzled LDS ==================
__device__ __forceinline__ void ktile6464_loop(
    const unsigned short* __restrict__ Ag, const unsigned short* __restrict__ Bg,
    int ldA, int ldB, int kEnd,
    unsigned short* As, unsigned short* Bs, v4f acc[2][2]) {
  const int tid  = threadIdx.x;
  const int lane = tid & 63;
  const int wr   = ((tid >> 6) & 1) << 5, wc = (tid >> 7) << 5;
  const int quad = lane >> 4, l16 = lane & 15;
  const int srow = tid >> 3;
  const int scol = ((tid ^ srow) & 7) * 8;   // XOR-swizzled global granule
  for (int k0 = 0; k0 < kEnd; k0 += 64) {
    __syncthreads();
#pragma unroll
    for (int it = 0; it < 2; ++it) {
      const unsigned short* ga = Ag + (size_t)(srow + it * 32) * ldA + k0 + scol;
      unsigned short* la = As + (size_t)(it * 256 + (tid & ~63)) * 8;
      __builtin_amdgcn_global_load_lds((const __attribute__((address_space(1))) void*)ga,
                                       (__attribute__((address_space(3))) void*)la, 16, 0, 0);
    }
#pragma unroll
    for (int it = 0; it < 2; ++it) {
      const unsigned short* gb = Bg + (size_t)(srow + it * 32) * ldB + k0 + scol;
      unsigned short* lb = Bs + (size_t)(it * 256 + (tid & ~63)) * 8;
      __builtin_amdgcn_global_load_lds((const __attribute__((address_space(1))) void*)gb,
                                       (__attribute__((address_space(3))) void*)lb, 16, 0, 0);
    }
    asm volatile("s_waitcnt vmcnt(0)" ::: "memory");
    __syncthreads();
#pragma unroll
    for (int kk = 0; kk < 64; kk += 32) {
      const int co = ((((kk >> 3) + quad) ^ (l16 & 7)) << 3);
      v8bf af[2], bfv[2];
#pragma unroll
      for (int i = 0; i < 2; ++i)
        af[i] = *(const v8bf*)(As + (wr + i * 16 + l16) * 64 + co);
#pragma unroll
      for (int i = 0; i < 2; ++i)
        bfv[i] = *(const v8bf*)(Bs + (wc + i * 16 + l16) * 64 + co);
#pragma unroll
      for (int mi = 0; mi < 2; ++mi)
#pragma unroll
        for (int ni = 0; ni < 2; ++ni)
          acc[mi][ni] = __builtin_amdgcn_mfma_f32_16x16x32_bf16(af[mi], bfv[ni], acc[mi][ni], 0, 0, 0);
    }
  }
}

#define PROLOG128                                                     \
  __shared__ __attribute__((aligned(16))) unsigned short smem[2][128 * 64];\
  unsigned short* As = smem[0];                                       \
  unsigned short* Bs = smem[1];                                       \
  v4f acc[4][4];                                                      \
  _Pragma("unroll") for (int i_ = 0; i_ < 4; ++i_)                    \
  _Pragma("unroll") for (int j_ = 0; j_ < 4; ++j_)                    \
      acc[i_][j_] = v4f{0.f, 0.f, 0.f, 0.f};                          \
  const int lane = threadIdx.x & 63, w = threadIdx.x >> 6;            \
  const int wm = (w & 1) << 6, wn = (w >> 1) << 6;                    \
  const int quad = lane >> 4, l16 = lane & 15;

#define PROLOG6464                                                    \
  __shared__ __attribute__((aligned(16))) unsigned short As[64 * 64]; \
  __shared__ __attribute__((aligned(16))) unsigned short Bs[64 * 64]; \
  v4f acc[2][2];                                                      \
  _Pragma("unroll") for (int i_ = 0; i_ < 2; ++i_)                    \
  _Pragma("unroll") for (int j_ = 0; j_ < 2; ++j_)                    \
      acc[i_][j_] = v4f{0.f, 0.f, 0.f, 0.f};                          \
  const int lane = threadIdx.x & 63, w = threadIdx.x >> 6;            \
  const int wr = (w & 1) << 5, wc = (w >> 1) << 5;                    \
  const int quad = lane >> 4, l16 = lane & 15;

// ------- fused QKV: X[8192,1024] @ Wqkv[3072,1024]^T -----------------------
// XCD-slab swizzle (VERIFIED round 5: FETCH 77->49MB).
__global__ __launch_bounds__(256) void gemm_qkv_fused_kernel(
    const unsigned short* __restrict__ X, const unsigned short* __restrict__ Wqkv,
    const float* __restrict__ bq, const float* __restrict__ bk,
    const float* __restrict__ bv, unsigned short* __restrict__ q_b,
    unsigned short* __restrict__ k_b, unsigned short* __restrict__ v_t) {
  PROLOG128
  int lid = blockIdx.y * 24 + blockIdx.x;
  int xcd = lid & 7, slot = lid >> 3;
  int by = (xcd << 3) | (slot & 7);   // 0..63
  int bx = slot >> 3;                 // 0..23
  int m0 = by * 128, n0 = bx * 128;
  gemm_ktile_loop(X + (size_t)m0 * DIM, Wqkv + (size_t)n0 * DIM, DIM, DIM, 0, DIM, As, Bs, acc);
  int region = n0 >> 10;  // 0:q 1:k 2:v (block-uniform)
  const float* bias = region == 0 ? bq : region == 1 ? bk : bv;
  int cbase = n0 & 1023;
  if (region < 2) {
    unsigned short* dst = region == 0 ? q_b : k_b;
#pragma unroll
    for (int mi = 0; mi < 4; ++mi) {
      int row0 = m0 + wm + mi * 16 + quad * 4;
#pragma unroll
      for (int ni = 0; ni < 4; ++ni) {
        int col = cbase + wn + ni * 16 + l16;
        float bcol = bias[col];
#pragma unroll
        for (int r = 0; r < 4; ++r)
          dst[(size_t)(row0 + r) * DIM + col] = f2bf(acc[mi][ni][r] + bcol);
      }
    }
  } else {
    // transpose tile through LDS, then coalesced 256B feature-row stores
    unsigned short* T = &smem[0][0];
    __syncthreads();
#pragma unroll
    for (int mi = 0; mi < 4; ++mi) {
      int trow = wm + mi * 16 + quad * 4;
#pragma unroll
      for (int ni = 0; ni < 4; ++ni) {
        int fcol = wn + ni * 16 + l16;
        float bcol = bias[cbase + fcol];
        ushort4 pk;
        pk.x = f2bf(acc[mi][ni][0] + bcol);
        pk.y = f2bf(acc[mi][ni][1] + bcol);
        pk.z = f2bf(acc[mi][ni][2] + bcol);
        pk.w = f2bf(acc[mi][ni][3] + bcol);
        *(ushort4*)(T + fcol * 128 + trow) = pk;
      }
    }
    __syncthreads();
    int bb = m0 >> 11, tok0 = m0 & (N_TOK - 1);
    unsigned short* dstb = v_t + ((size_t)(bb << 10) + cbase) * N_TOK + tok0;
#pragma unroll
    for (int kk2 = 0; kk2 < 8; ++kk2) {
      int c = kk2 * 256 + threadIdx.x;
      int f = c >> 4, e0 = (c & 15) * 8;
      v8us v = *(const v8us*)(T + f * 128 + e0);
      *(v8us*)(dstb + (size_t)f * N_TOK + e0) = v;
    }
  }
}

// ------- scores: 64x64 tiles, triangular (528/batch, 2112 blocks) ----------
__global__ __launch_bounds__(256) void gemm_scores_kernel(
    const unsigned short* __restrict__ q, const unsigned short* __restrict__ k,
    const float2* __restrict__ qp, const float* __restrict__ thr,
    unsigned short* __restrict__ S) {
  PROLOG6464
  int b = blockIdx.y;
  int bx = blockIdx.x;
  int t = (bx & 7) * 66 + (bx >> 3);  // 528 = 8 XCDs x 66 contiguous tiles
  int ti = (int)((sqrtf(8.f * (float)t + 1.f) - 1.f) * 0.5f);
  while ((ti + 1) * (ti + 2) / 2 <= t) ++ti;
  while (ti * (ti + 1) / 2 > t) --ti;
  int tj = t - ti * (ti + 1) / 2;
  int i0 = ti * 64, j0 = tj * 64;
  const unsigned short* qb = q + (size_t)b * N_TOK * DIM;
  const unsigned short* kb = k + (size_t)b * N_TOK * DIM;
  ktile6464_loop(qb + (size_t)i0 * DIM, kb + (size_t)j0 * DIM, DIM, DIM, DIM, As, Bs, acc);
  float th = thr[b];
  const float2* qpb = qp + ((size_t)b << 11);
  unsigned short* Sb = S + (size_t)b * N_TOK * N_TOK;
  float2 pjv[2];
#pragma unroll
  for (int ni = 0; ni < 2; ++ni) pjv[ni] = qpb[j0 + wc + ni * 16 + l16];
#pragma unroll
  for (int mi = 0; mi < 2; ++mi) {
#pragma unroll
    for (int r = 0; r < 4; ++r) {
      int i = i0 + wr + mi * 16 + quad * 4 + r;
      float2 pi2 = qpb[i];
#pragma unroll
      for (int ni = 0; ni < 2; ++ni) {
        int j = j0 + wc + ni * 16 + l16;
        if (j <= i) {
          float dx = pi2.x - pjv[ni].x, dy = pi2.y - pjv[ni].y;
          float dd = __fadd_rn(__fmul_rn(dx, dx), __fmul_rn(dy, dy));
          bool ok = (dd <= th);
          // forward_bias==0 only when cos(atan2) rounds to -1 (dx<0, |dy| tiny)
          if (ok && dx < 0.f && fabsf(dy) <= 3e-4f * (-dx)) {
            float fb = 0.5f * (1.f + cosf(atan2f(dy, dx)));
            if (fb == 0.f) ok = false;
          }
          Sb[(size_t)i * N_TOK + j] = ok ? f2bf(acc[mi][ni][r] * 0.03125f) : 0xFF80; // -inf bf16
        }
      }
    }
  }
}

// ------- row softmax: S bf16 (j<=i) -> P bf16 (full row), vectorized -------
__global__ __launch_bounds__(256) void softmax_kernel(
    const unsigned short* __restrict__ S, unsigned short* __restrict__ P) {
  int row = blockIdx.x;
  int b = row >> 11, i = row & (N_TOK - 1);
  const unsigned short* s = S + ((size_t)b * N_TOK + i) * N_TOK;
  unsigned short* p = P + ((size_t)b * N_TOK + i) * N_TOK;
  int tid = threadIdx.x, lane = tid & 63, w = tid >> 6;
  int lim = i + 1;
  int tail0 = lim & ~7, ntail = lim - tail0;
  __shared__ float redmax[4], redsum[4];
  float mx = -__builtin_inff();
  for (int j = tid * 8; j + 8 <= lim; j += 2048) {
    v8us v = *(const v8us*)(s + j);
#pragma unroll
    for (int e = 0; e < 8; ++e) mx = fmaxf(mx, bf2f(v[e]));
  }
  if (tid < ntail) mx = fmaxf(mx, bf2f(s[tail0 + tid]));
  for (int o = 32; o; o >>= 1) mx = fmaxf(mx, __shfl_xor(mx, o));
  if (lane == 0) redmax[w] = mx;
  __syncthreads();
  mx = fmaxf(fmaxf(redmax[0], redmax[1]), fmaxf(redmax[2], redmax[3]));
  float sum = 0.f;
  for (int j = tid * 8; j + 8 <= lim; j += 2048) {
    v8us v = *(const v8us*)(s + j);
#pragma unroll
    for (int e = 0; e < 8; ++e) sum += __expf(bf2f(v[e]) - mx);
  }
  if (tid < ntail) sum += __expf(bf2f(s[tail0 + tid]) - mx);
  for (int o = 32; o; o >>= 1) sum += __shfl_xor(sum, o);
  if (lane == 0) redsum[w] = sum;
  __syncthreads();
  sum = redsum[0] + redsum[1] + redsum[2] + redsum[3];
  float inv = 1.f / sum;
  for (int j = tid * 8; j + 8 <= lim; j += 2048) {
    v8us v = *(const v8us*)(s + j);
    v8us o;
#pragma unroll
    for (int e = 0; e < 8; ++e) o[e] = f2bf(__expf(bf2f(v[e]) - mx) * inv);
    *(v8us*)(p + j) = o;
  }
  if (tid < ntail) p[tail0 + tid] = f2bf(__expf(bf2f(s[tail0 + tid]) - mx) * inv);
  int zs = (lim + 7) & ~7;
  if (tid < zs - lim) p[lim + tid] = 0;
  v8us zv;
#pragma unroll
  for (int e = 0; e < 8; ++e) zv[e] = 0;
  for (int j = zs + tid * 8; j < N_TOK; j += 2048) *(v8us*)(p + j) = zv;
}

// ------- context = P @ v (v transposed), 64x64 tiles, triangular K --------
__global__ __launch_bounds__(256) void gemm_pv_kernel(
    const unsigned short* __restrict__ P, const unsigned short* __restrict__ vt,
    unsigned short* __restrict__ ctx) {
  PROLOG6464
  int b = blockIdx.z;
  int ti = blockIdx.y, d0 = blockIdx.x * 64;
  int i0 = ti * 64;
  const unsigned short* Pb = P + (size_t)b * N_TOK * N_TOK;
  const unsigned short* Vb = vt + ((size_t)b * DIM + d0) * N_TOK;
  int kEnd = (ti + 1) * 64;  // P[i][j]==0 for j>i
  ktile6464_loop(Pb + (size_t)i0 * N_TOK, Vb, N_TOK, N_TOK, kEnd, As, Bs, acc);
#pragma unroll
  for (int mi = 0; mi < 2; ++mi) {
    int row0 = i0 + wr + mi * 16 + quad * 4;
#pragma unroll
    for (int ni = 0; ni < 2; ++ni) {
      int d = d0 + wc + ni * 16 + l16;
#pragma unroll
      for (int r = 0; r < 4; ++r)
        ctx[((size_t)b * N_TOK + row0 + r) * DIM + d] = f2bf(acc[mi][ni][r]);
    }
  }
}

// ------- out = hs + ctx@Wo^T + bo + 0.1*(r_embed@Wfq^T + bfq), 64x64 ------
__global__ __launch_bounds__(256) void gemm_out_kernel(
    const unsigned short* __restrict__ ctx, const unsigned short* __restrict__ Wob,
    const float* __restrict__ bo, const float* __restrict__ hs,
    const float2* __restrict__ remb, const float* __restrict__ Wfq,
    const float* __restrict__ bfq, float* __restrict__ out) {
  PROLOG6464
  int lid = blockIdx.y * 16 + blockIdx.x;
  int xcd = lid & 7, slot = lid >> 3;
  int by = (xcd << 4) | (slot & 15);  // 0..127 (16-row slab per XCD)
  int bx = slot >> 4;                 // 0..15
  int m0 = by * 64, n0 = bx * 64;
  ktile6464_loop(ctx + (size_t)m0 * DIM, Wob + (size_t)n0 * DIM, DIM, DIM, DIM, As, Bs, acc);
#pragma unroll
  for (int mi = 0; mi < 2; ++mi) {
    int row0 = m0 + wr + mi * 16 + quad * 4;
#pragma unroll
    for (int ni = 0; ni < 2; ++ni) {
      int col = n0 + wc + ni * 16 + l16;
      float bias2 = bo[col] + 0.1f * bfq[col];
      float wf0 = 0.1f * Wfq[col * 2 + 0], wf1 = 0.1f * Wfq[col * 2 + 1];
#pragma unroll
      for (int r = 0; r < 4; ++r) {
        int row = row0 + r;
        float2 re = remb[row];
        out[(size_t)row * DIM + col] =
            acc[mi][ni][r] + bias2 + hs[(size_t)row * DIM + col] + re.x * wf0 + re.y * wf1;
      }
    }
  }
}

extern "C" void kernel_launch(void* const* d_in, const int* in_sizes, int n_in,
                              void* d_out, int out_size, void* d_ws, size_t ws_size,
                              hipStream_t stream) {
  const float* hs  = (const float*)d_in[0];
  const float* Wq  = (const float*)d_in[1];
  const float* bq  = (const float*)d_in[2];
  const float* Wk  = (const float*)d_in[3];
  const float* bk  = (const float*)d_in[4];
  const float* Wv  = (const float*)d_in[5];
  const float* bv  = (const float*)d_in[6];
  const float* Wo  = (const float*)d_in[7];
  const float* bo  = (const float*)d_in[8];
  const float* Wtq = (const float*)d_in[9];
  const float* btq = (const float*)d_in[10];
  const float* Wfq = (const float*)d_in[11];
  const float* bfq = (const float*)d_in[12];
  float* out = (float*)d_out;

  char* ws = (char*)d_ws;
  size_t off = 0;
  auto alloc = [&](size_t bytes) {
    char* p = ws + off;
    off += (bytes + 255) & ~(size_t)255;
    return p;
  };
  unsigned short* hs_b = (unsigned short*)alloc((size_t)8192 * 1024 * 2);  // 16.8MB
  unsigned short* q_b  = (unsigned short*)alloc((size_t)8192 * 1024 * 2);
  unsigned short* k_b  = (unsigned short*)alloc((size_t)8192 * 1024 * 2);  // contiguous after q_b (P alias)
  unsigned short* v_t  = (unsigned short*)alloc((size_t)8192 * 1024 * 2);
  // Wq_b/Wk_b/Wv_b MUST stay contiguous: fused QKV uses them as one [3072,1024].
  unsigned short* Wq_b = (unsigned short*)alloc((size_t)1024 * 1024 * 2);
  unsigned short* Wk_b = (unsigned short*)alloc((size_t)1024 * 1024 * 2);
  unsigned short* Wv_b = (unsigned short*)alloc((size_t)1024 * 1024 * 2);
  unsigned short* Wo_b = (unsigned short*)alloc((size_t)1024 * 1024 * 2);
  float2* qp   = (float2*)alloc((size_t)8192 * 8);
  float2* remb = (float2*)alloc((size_t)8192 * 8);
  double* part = (double*)alloc((size_t)BATCH * 64 * 2 * 8);
  float*  thr  = (float*)alloc(64);
  unsigned short* S = (unsigned short*)alloc((size_t)BATCH * N_TOK * N_TOK * 2);  // 33.6MB bf16
  // Aliases (lifetimes disjoint): P over q_b+k_b (33.6MB, both dead after
  // scores), ctx over hs_b (dead after QKV).
  unsigned short* P   = q_b;
  unsigned short* ctx = hs_b;

  castqp_kernel<<<2048, 256, 0, stream>>>(hs, Wtq, btq, hs_b, qp, remb);
  cast_w4_kernel<<<dim3(1024, 4), 256, 0, stream>>>(Wq, Wk, Wv, Wo, Wq_b, Wk_b, Wv_b, Wo_b);
  moments_kernel<<<dim3(64, BATCH), 256, 0, stream>>>((const float2*)qp, part);
  thr_kernel<<<1, 256, 0, stream>>>(part, thr);

  gemm_qkv_fused_kernel<<<dim3(24, 64), 256, 0, stream>>>(
      hs_b, Wq_b, bq, bk, bv, q_b, k_b, v_t);

  gemm_scores_kernel<<<dim3(528, 4), 256, 0, stream>>>(
      q_b, k_b, (const float2*)qp, thr, S);

  softmax_kernel<<<8192, 256, 0, stream>>>(S, P);

  gemm_pv_kernel<<<dim3(16, 32, 4), 256, 0, stream>>>(P, v_t, ctx);

  gemm_out_kernel<<<dim3(16, 128), 256, 0, stream>>>(ctx, Wo_b, bo, hs, remb, Wfq, bfq, out);
}